// Round 5
// baseline (696.884 us; speedup 1.0000x reference)
//
#include <hip/hip_runtime.h>
#include <math.h>

#define NBAT 8
#define NC   256
#define NH   96
#define NW   96
#define NP   9216
#define NCQ  32
#define NKC  6
#define NL   192
#define NV   320          // 256 v-channels + 32 q + 32 k
#define NTOT 73728        // NBAT*NP

typedef __attribute__((ext_vector_type(4))) float  floatx4;
typedef __attribute__((ext_vector_type(8))) short  short8;

// ---------- bf16 helpers (storage only; math fp32) ----------
__device__ __forceinline__ float bf2f(unsigned short h){
  return __uint_as_float(((unsigned)h) << 16);
}
__device__ __forceinline__ float bflo(unsigned u){ return __uint_as_float(u << 16); }
__device__ __forceinline__ float bfhi(unsigned u){ return __uint_as_float(u & 0xFFFF0000u); }
__device__ __forceinline__ unsigned short f2bf(float f){
  unsigned u = __float_as_uint(f);
  u += 0x7FFFu + ((u >> 16) & 1u);
  return (unsigned short)(u >> 16);
}

union F4 { float4 v; float a[4]; };

// ---------- reductions ----------
__device__ __forceinline__ float warpReduceSum(float v){
  #pragma unroll
  for (int m = 32; m; m >>= 1) v += __shfl_xor(v, m);
  return v;
}
__device__ __forceinline__ float warpReduceMax(float v){
  #pragma unroll
  for (int m = 32; m; m >>= 1) v = fmaxf(v, __shfl_xor(v, m));
  return v;
}
__device__ float blockReduceSum(float v){
  __shared__ float lds[8];
  v = warpReduceSum(v);
  int wid = threadIdx.x >> 6, lane = threadIdx.x & 63;
  int nw = blockDim.x >> 6;
  if (lane == 0) lds[wid] = v;
  __syncthreads();
  if (wid == 0){
    v = (lane < nw) ? lds[lane] : 0.f;
    #pragma unroll
    for (int m = 4; m; m >>= 1) v += __shfl_xor(v, m);
  }
  __syncthreads();
  return v;  // valid on thread 0
}
__device__ float blockReduceMax(float v){
  __shared__ float lds[8];
  v = warpReduceMax(v);
  int wid = threadIdx.x >> 6, lane = threadIdx.x & 63;
  int nw = blockDim.x >> 6;
  if (lane == 0) lds[wid] = v;
  __syncthreads();
  if (wid == 0){
    v = (lane < nw) ? lds[lane] : -INFINITY;
    #pragma unroll
    for (int m = 4; m; m >>= 1) v = fmaxf(v, __shfl_xor(v, m));
  }
  __syncthreads();
  return v;
}

// ---------- 1. per-channel stats (float4 vectorized) ----------
__global__ __launch_bounds__(256)
void k_stats(const float* __restrict__ S, const float* __restrict__ T,
             float* __restrict__ s_sum, float* __restrict__ s_sq){
  int blk = blockIdx.x;                 // 2*C*B = 4096
  int t = blk / (NC * NBAT);
  int rem = blk % (NC * NBAT);
  int c = rem / NBAT;
  int n = rem % NBAT;
  const float4* x4 = (const float4*)((t ? T : S) + ((size_t)n * NC + c) * NP);
  float s = 0.f, q = 0.f;
  for (int p = threadIdx.x; p < NP / 4; p += 256){
    F4 f; f.v = x4[p];
    #pragma unroll
    for (int j = 0; j < 4; j++){ s += f.a[j]; q += f.a[j] * f.a[j]; }
  }
  s = blockReduceSum(s);
  q = blockReduceSum(q);
  if (threadIdx.x == 0){
    atomicAdd(&s_sum[t * NC + c], s);
    atomicAdd(&s_sq[t * NC + c], q);
  }
}

__global__ __launch_bounds__(512)
void k_finalize(const float* __restrict__ s_sum, const float* __restrict__ s_sq,
                float* __restrict__ mean, float* __restrict__ inv){
  int i = threadIdx.x;
  if (i < 2 * NC){
    float s = s_sum[i], q = s_sq[i];
    float m = s / (float)NTOT;
    float var = (q - s * m) / (float)(NTOT - 1);
    var = fmaxf(var, 0.f);
    mean[i] = m;
    inv[i] = 1.f / (sqrtf(var) + 1e-6f);
  }
}

// ---------- 2. stage normalized x as bf16 XN[b][p][c] (transpose) ----------
__global__ __launch_bounds__(256)
void k_xn(const float* __restrict__ x0, int b0,
          const float* __restrict__ mean, const float* __restrict__ inv, int t,
          unsigned short* __restrict__ XN){
  int pt = blockIdx.x, ct = blockIdx.y, bb = blockIdx.z;  // (144, 4, NB)
  int bg = b0 + bb;
  int p0 = pt * 64, c0 = ct * 64;
  __shared__ float tile[64 * 65];
  const float* x = x0 + ((size_t)bg * NC + c0) * NP + p0;
  #pragma unroll
  for (int i = 0; i < 4; i++){
    int idx = threadIdx.x + i * 256;       // 64 c-rows x 16 float4 groups
    int r = idx >> 4, g = (idx & 15) * 4;
    F4 f; f.v = *(const float4*)(x + (size_t)r * NP + g);
    float m = mean[t * NC + c0 + r], iv = inv[t * NC + c0 + r];
    #pragma unroll
    for (int j = 0; j < 4; j++) tile[(g + j) * 65 + r] = (f.a[j] - m) * iv;
  }
  __syncthreads();
  #pragma unroll
  for (int i = 0; i < 4; i++){
    int idx = threadIdx.x + i * 256;       // 64 p-rows x 16 groups of 4c
    int p = idx >> 4, g = (idx & 15) * 4;
    unsigned lo = (unsigned)f2bf(tile[p * 65 + g + 0]) | ((unsigned)f2bf(tile[p * 65 + g + 1]) << 16);
    unsigned hi = (unsigned)f2bf(tile[p * 65 + g + 2]) | ((unsigned)f2bf(tile[p * 65 + g + 3]) << 16);
    uint2 u; u.x = lo; u.y = hi;
    *(uint2*)(XN + ((size_t)bb * NP + p0 + p) * NC + c0 + g) = u;
  }
}

// ---------- 2b. pre-convert W (v|q|k) to bf16 Wb[320][256] ----------
__global__ __launch_bounds__(256)
void k_wconv(const float* __restrict__ wv, const float* __restrict__ wq,
             const float* __restrict__ wk, unsigned short* __restrict__ Wb){
  int n = blockIdx.x;         // 320
  const float* src = (n < 256) ? (wv + (size_t)n * NC)
                   : (n < 288) ? (wq + (size_t)(n - 256) * NC)
                               : (wk + (size_t)(n - 288) * NC);
  Wb[(size_t)n * NC + threadIdx.x] = f2bf(src[threadIdx.x]);
}

// ---------- 3. causal attention from XN ----------
// M[bb][k][p] = sum_c wcls[k][c] * XN[bb][p][c]
__global__ __launch_bounds__(256)
void k_caMB(const unsigned short* __restrict__ XN, const float* __restrict__ wcls,
            float* __restrict__ smca){
  int pt = blockIdx.x, bb = blockIdx.y;   // (36, NB)
  __shared__ float wl[NKC * NC];
  for (int idx = threadIdx.x; idx < NKC * NC; idx += 256) wl[idx] = wcls[idx];
  __syncthreads();
  int p = pt * 256 + threadIdx.x;
  const unsigned short* xr = XN + ((size_t)bb * NP + p) * NC;
  float acc[NKC] = {};
  for (int g = 0; g < 32; g++){
    short8 x8 = *(const short8*)(xr + g * 8);
    #pragma unroll
    for (int e = 0; e < 8; e++){
      float xv = bf2f(((unsigned short*)&x8)[e]);
      int c = g * 8 + e;
      #pragma unroll
      for (int k = 0; k < NKC; k++) acc[k] += wl[k * NC + c] * xv;
    }
  }
  #pragma unroll
  for (int k = 0; k < NKC; k++) smca[((size_t)bb * NKC + k) * NP + p] = acc[k];
}

__global__ __launch_bounds__(256)
void k_caSoftmax(float* __restrict__ smca){
  int r = blockIdx.x;                      // NB*NKC rows
  float* row = smca + (size_t)r * NP;
  float m = -INFINITY;
  for (int p = threadIdx.x; p < NP; p += 256) m = fmaxf(m, row[p]);
  m = blockReduceMax(m);
  __shared__ float bm, bs;
  if (threadIdx.x == 0) bm = m;
  __syncthreads();
  m = bm;
  float s = 0.f;
  for (int p = threadIdx.x; p < NP; p += 256) s += expf(row[p] - m);
  s = blockReduceSum(s);
  if (threadIdx.x == 0) bs = 1.f / s;
  __syncthreads();
  float rs = bs;
  for (int p = threadIdx.x; p < NP; p += 256) row[p] = expf(row[p] - m) * rs;
}

// ca[t][n][k][c] += sum_p sm[k][p] * XN[n][p][c]   (split-K over p, 8 slices)
__global__ __launch_bounds__(256)
void k_caOutB(const unsigned short* __restrict__ XN, const float* __restrict__ smca,
              float* __restrict__ ca, int t, int b0){
  int ks = blockIdx.x, bb = blockIdx.y;   // (8, NB)
  __shared__ float sml[NKC * 1152];       // 27.6 KB
  __shared__ float lca[NKC * NC];         // 6 KB
  int p0 = ks * 1152;
  const float* smb = smca + (size_t)bb * NKC * NP;
  for (int idx = threadIdx.x; idx < NKC * 1152; idx += 256){
    int k = idx / 1152, pp = idx % 1152;
    sml[idx] = smb[(size_t)k * NP + p0 + pp];
  }
  for (int idx = threadIdx.x; idx < NKC * NC; idx += 256) lca[idx] = 0.f;
  __syncthreads();
  int c8 = (threadIdx.x & 31) * 8, psub = threadIdx.x >> 5;
  const unsigned short* xb = XN + (size_t)bb * NP * NC;
  float acc[NKC][8] = {};
  for (int j = 0; j < 144; j++){
    int pp = psub + 8 * j;
    short8 x8 = *(const short8*)(xb + (size_t)(p0 + pp) * NC + c8);
    float xf[8];
    #pragma unroll
    for (int e = 0; e < 8; e++) xf[e] = bf2f(((unsigned short*)&x8)[e]);
    #pragma unroll
    for (int k = 0; k < NKC; k++){
      float sv = sml[k * 1152 + pp];
      #pragma unroll
      for (int e = 0; e < 8; e++) acc[k][e] += sv * xf[e];
    }
  }
  #pragma unroll
  for (int k = 0; k < NKC; k++)
    #pragma unroll
    for (int e = 0; e < 8; e++) atomicAdd(&lca[k * NC + c8 + e], acc[k][e]);
  __syncthreads();
  int n = b0 + bb;
  #pragma unroll
  for (int k = 0; k < NKC; k++)
    atomicAdd(&ca[((size_t)(t * NBAT + n) * NKC + k) * NC + threadIdx.x],
              lca[k * NC + threadIdx.x]);
}

__global__ __launch_bounds__(256)
void k_caLoss(const float* __restrict__ ca, float* __restrict__ out){
  int i = blockIdx.x * 256 + threadIdx.x;   // 12288 total
  float d = 0.f;
  if (i < NBAT * NKC * NC) d = ca[(size_t)NBAT * NKC * NC + i] - ca[i];
  float ss = blockReduceSum(d * d);
  if (threadIdx.x == 0) atomicAdd(out, ss * (0.0005f / 8.0f));
}

// ---------- 4. MFMA GEMM: XN[p x 256] @ Wb^T -> VT1[b][c][p] + q,k [p][cq] ----------
__global__ __launch_bounds__(256)
void k_v(const unsigned short* __restrict__ XN, const unsigned short* __restrict__ Wb,
         const float* __restrict__ bv, const float* __restrict__ bq,
         const float* __restrict__ bk,
         unsigned short* __restrict__ VT1,
         unsigned short* __restrict__ qb, unsigned short* __restrict__ kb){
  int pt = blockIdx.x, bb = blockIdx.y;   // (144, NB)
  int p0 = pt * 64;
  __shared__ unsigned short Wl[NV * 40];
  int lane = threadIdx.x & 63;
  int wid = threadIdx.x >> 6;
  int col = lane & 15, quad = lane >> 4;
  const unsigned short* xnb = XN + (size_t)bb * NP * NC + (size_t)(p0 + wid * 16 + col) * NC;
  floatx4 acc[20];
  #pragma unroll
  for (int nt = 0; nt < 20; nt++) acc[nt] = (floatx4){0.f, 0.f, 0.f, 0.f};

  int ci_n[5], ci_k8[5];
  #pragma unroll
  for (int i = 0; i < 5; i++){ int ci = i * 256 + threadIdx.x; ci_n[i] = ci >> 2; ci_k8[i] = (ci & 3) * 8; }

  short8 w[5];
  #pragma unroll
  for (int i = 0; i < 5; i++)
    w[i] = *(const short8*)(Wb + (size_t)ci_n[i] * NC + ci_k8[i]);

  for (int ks = 0; ks < 8; ks++){
    if (ks) __syncthreads();
    #pragma unroll
    for (int i = 0; i < 5; i++)
      *(short8*)(Wl + ci_n[i] * 40 + ci_k8[i]) = w[i];
    __syncthreads();
    if (ks < 7){
      int k0n = (ks + 1) * 32;
      #pragma unroll
      for (int i = 0; i < 5; i++)
        w[i] = *(const short8*)(Wb + (size_t)ci_n[i] * NC + k0n + ci_k8[i]);
    }
    short8 a = *(const short8*)(xnb + ks * 32 + quad * 8);
    #pragma unroll
    for (int nt = 0; nt < 20; nt++){
      short8 b = *(const short8*)(Wl + (nt * 16 + col) * 40 + quad * 8);
      acc[nt] = __builtin_amdgcn_mfma_f32_16x16x32_bf16(a, b, acc[nt], 0, 0, 0);
    }
  }

  int prow0 = p0 + wid * 16 + quad * 4;
  #pragma unroll
  for (int nt = 0; nt < 16; nt++){
    int c = nt * 16 + col;
    float bias = bv[c];
    uint2 u;
    u.x = (unsigned)f2bf(acc[nt][0] + bias) | ((unsigned)f2bf(acc[nt][1] + bias) << 16);
    u.y = (unsigned)f2bf(acc[nt][2] + bias) | ((unsigned)f2bf(acc[nt][3] + bias) << 16);
    *(uint2*)(VT1 + ((size_t)bb * NC + c) * NP + prow0) = u;
  }
  #pragma unroll
  for (int nt = 16; nt < 18; nt++){
    int c = (nt - 16) * 16 + col;
    float bias = bq[c];
    #pragma unroll
    for (int i = 0; i < 4; i++)
      qb[((size_t)bb * NP + prow0 + i) * NCQ + c] = f2bf(acc[nt][i] + bias);
  }
  #pragma unroll
  for (int nt = 18; nt < 20; nt++){
    int c = (nt - 18) * 16 + col;
    float bias = bk[c];
    #pragma unroll
    for (int i = 0; i < 4; i++)
      kb[((size_t)bb * NP + prow0 + i) * NCQ + c] = f2bf(acc[nt][i] + bias);
  }
}

// ---------- 4b. spatial transpose: VT2[b][c][w*96+h] = VT1[b][c][h*96+w] ----------
__global__ __launch_bounds__(256)
void k_vt(const unsigned short* __restrict__ VT1, unsigned short* __restrict__ VT2){
  int c = blockIdx.x, bb = blockIdx.y;    // (256, NB)
  __shared__ unsigned short tile[96 * 104];
  size_t base = ((size_t)bb * NC + c) * NP;
  for (int idx = threadIdx.x; idx < 1152; idx += 256){
    int h = idx / 12, g = idx % 12;
    short8 v = *(const short8*)(VT1 + base + h * 96 + g * 8);
    #pragma unroll
    for (int kk = 0; kk < 8; kk++) tile[(g * 8 + kk) * 104 + h] = ((unsigned short*)&v)[kk];
  }
  __syncthreads();
  for (int idx = threadIdx.x; idx < 1152; idx += 256){
    int w = idx / 12, g = idx % 12;
    short8 v = *(const short8*)(tile + w * 104 + g * 8);
    *(short8*)(VT2 + base + w * 96 + g * 8) = v;
  }
}

// ---------- 5. eH scores (MFMA, diag masked): att[b][i*96+w][j], j<96 ----------
__global__ __launch_bounds__(256)
void k_eH(const unsigned short* __restrict__ qb, const unsigned short* __restrict__ kb,
          unsigned short* __restrict__ att){
  int w = blockIdx.x, bb = blockIdx.y;      // (96, NB)
  int lane = threadIdx.x & 63, wid = threadIdx.x >> 6;
  int col = lane & 15, quad = lane >> 4;
  int mi0 = (wid & 1) * 3, ni0 = (wid >> 1) * 3;
  short8 a[3], b[3];
  #pragma unroll
  for (int m = 0; m < 3; m++)
    a[m] = *(const short8*)(qb + ((size_t)bb * NP + ((mi0 + m) * 16 + col) * 96 + w) * NCQ + quad * 8);
  #pragma unroll
  for (int n = 0; n < 3; n++)
    b[n] = *(const short8*)(kb + ((size_t)bb * NP + ((ni0 + n) * 16 + col) * 96 + w) * NCQ + quad * 8);
  floatx4 acc[3][3];
  #pragma unroll
  for (int m = 0; m < 3; m++)
    #pragma unroll
    for (int n = 0; n < 3; n++){
      acc[m][n] = (floatx4){0.f, 0.f, 0.f, 0.f};
      acc[m][n] = __builtin_amdgcn_mfma_f32_16x16x32_bf16(a[m], b[n], acc[m][n], 0, 0, 0);
    }
  #pragma unroll
  for (int m = 0; m < 3; m++)
    #pragma unroll
    for (int n = 0; n < 3; n++){
      int j = (ni0 + n) * 16 + col;
      #pragma unroll
      for (int r = 0; r < 4; r++){
        int i = (mi0 + m) * 16 + quad * 4 + r;
        float v = (j == i) ? -INFINITY : acc[m][n][r];
        att[((size_t)bb * NP + i * 96 + w) * NL + j] = f2bf(v);
      }
    }
}

// ---------- 6. eW scores (MFMA): att[b][h*96+i][96+j] ----------
__global__ __launch_bounds__(256)
void k_eW(const unsigned short* __restrict__ qb, const unsigned short* __restrict__ kb,
          unsigned short* __restrict__ att){
  int h = blockIdx.x, bb = blockIdx.y;      // (96, NB)
  int lane = threadIdx.x & 63, wid = threadIdx.x >> 6;
  int col = lane & 15, quad = lane >> 4;
  int mi0 = (wid & 1) * 3, ni0 = (wid >> 1) * 3;
  short8 a[3], b[3];
  #pragma unroll
  for (int m = 0; m < 3; m++)
    a[m] = *(const short8*)(qb + ((size_t)bb * NP + h * 96 + (mi0 + m) * 16 + col) * NCQ + quad * 8);
  #pragma unroll
  for (int n = 0; n < 3; n++)
    b[n] = *(const short8*)(kb + ((size_t)bb * NP + h * 96 + (ni0 + n) * 16 + col) * NCQ + quad * 8);
  floatx4 acc[3][3];
  #pragma unroll
  for (int m = 0; m < 3; m++)
    #pragma unroll
    for (int n = 0; n < 3; n++){
      acc[m][n] = (floatx4){0.f, 0.f, 0.f, 0.f};
      acc[m][n] = __builtin_amdgcn_mfma_f32_16x16x32_bf16(a[m], b[n], acc[m][n], 0, 0, 0);
    }
  #pragma unroll
  for (int m = 0; m < 3; m++)
    #pragma unroll
    for (int n = 0; n < 3; n++){
      int j = (ni0 + n) * 16 + col;
      #pragma unroll
      for (int r = 0; r < 4; r++){
        int i = (mi0 + m) * 16 + quad * 4 + r;
        att[((size_t)bb * NP + h * 96 + i) * NL + 96 + j] = f2bf(acc[m][n][r]);
      }
    }
}

// ---------- 7. softmax over 192 per query ----------
__global__ __launch_bounds__(256)
void k_attSoftmax(unsigned short* __restrict__ att){
  int q = blockIdx.x * 4 + (threadIdx.x >> 6);
  int lane = threadIdx.x & 63;
  unsigned short* row = att + (size_t)q * NL;
  float e0 = bf2f(row[lane]);
  float e1 = bf2f(row[64 + lane]);
  float e2 = bf2f(row[128 + lane]);
  float m = fmaxf(e0, fmaxf(e1, e2));
  m = warpReduceMax(m);
  float x0 = expf(e0 - m), x1 = expf(e1 - m), x2 = expf(e2 - m);
  float s = warpReduceSum(x0 + x1 + x2);
  float rs = 1.f / s;
  row[lane]       = f2bf(x0 * rs);
  row[64 + lane]  = f2bf(x1 * rs);
  row[128 + lane] = f2bf(x2 * rs);
}

// ---------- 8. outH (MFMA, D[c][i]): OH[i*96+w][c] = sum_j attH[(i,w),j]*VT2[c][w*96+j]
__global__ __launch_bounds__(256)
void k_outH(const unsigned short* __restrict__ VT2, const unsigned short* __restrict__ att,
            unsigned short* __restrict__ OH){
  int w = blockIdx.x, bb = blockIdx.y;    // (96, NB)
  int lane = threadIdx.x & 63, wid = threadIdx.x >> 6;
  int col = lane & 15, quad = lane >> 4;
  floatx4 acc[4][6];
  #pragma unroll
  for (int ct = 0; ct < 4; ct++)
    #pragma unroll
    for (int it = 0; it < 6; it++) acc[ct][it] = (floatx4){0.f, 0.f, 0.f, 0.f};
  #pragma unroll
  for (int ks = 0; ks < 3; ks++){
    int k0 = ks * 32 + quad * 8;
    short8 a[4], b[6];
    #pragma unroll
    for (int ct = 0; ct < 4; ct++){
      int c = wid * 64 + ct * 16 + col;
      a[ct] = *(const short8*)(VT2 + ((size_t)bb * NC + c) * NP + w * 96 + k0);
    }
    #pragma unroll
    for (int it = 0; it < 6; it++){
      int i = it * 16 + col;
      b[it] = *(const short8*)(att + ((size_t)bb * NP + i * 96 + w) * NL + k0);
    }
    #pragma unroll
    for (int ct = 0; ct < 4; ct++)
      #pragma unroll
      for (int it = 0; it < 6; it++)
        acc[ct][it] = __builtin_amdgcn_mfma_f32_16x16x32_bf16(a[ct], b[it], acc[ct][it], 0, 0, 0);
  }
  #pragma unroll
  for (int ct = 0; ct < 4; ct++)
    #pragma unroll
    for (int it = 0; it < 6; it++){
      int c0 = wid * 64 + ct * 16 + quad * 4;
      int i = it * 16 + col;
      uint2 u;
      u.x = (unsigned)f2bf(acc[ct][it][0]) | ((unsigned)f2bf(acc[ct][it][1]) << 16);
      u.y = (unsigned)f2bf(acc[ct][it][2]) | ((unsigned)f2bf(acc[ct][it][3]) << 16);
      *(uint2*)(OH + ((size_t)bb * NP + i * 96 + w) * NC + c0) = u;
    }
}

// ---------- 9. outW (MFMA, D[c][i]); T pass: OtL = g*(OH+outW) + t_n; S: fused loss
__global__ __launch_bounds__(256)
void k_outW(const unsigned short* __restrict__ VT1, const unsigned short* __restrict__ att,
            const unsigned short* __restrict__ OH, unsigned short* __restrict__ OtL,
            const unsigned short* __restrict__ XN,
            const float* __restrict__ gamma, int spass,
            float* __restrict__ out){
  int h = blockIdx.x, bb = blockIdx.y;    // (96, NB)
  int lane = threadIdx.x & 63, wid = threadIdx.x >> 6;
  int col = lane & 15, quad = lane >> 4;
  float g = gamma[0];
  floatx4 acc[4][6];
  #pragma unroll
  for (int ct = 0; ct < 4; ct++)
    #pragma unroll
    for (int it = 0; it < 6; it++) acc[ct][it] = (floatx4){0.f, 0.f, 0.f, 0.f};
  #pragma unroll
  for (int ks = 0; ks < 3; ks++){
    int k0 = ks * 32 + quad * 8;
    short8 a[4], b[6];
    #pragma unroll
    for (int ct = 0; ct < 4; ct++){
      int c = wid * 64 + ct * 16 + col;
      a[ct] = *(const short8*)(VT1 + ((size_t)bb * NC + c) * NP + h * 96 + k0);
    }
    #pragma unroll
    for (int it = 0; it < 6; it++){
      int i = it * 16 + col;
      b[it] = *(const short8*)(att + ((size_t)bb * NP + h * 96 + i) * NL + 96 + k0);
    }
    #pragma unroll
    for (int ct = 0; ct < 4; ct++)
      #pragma unroll
      for (int it = 0; it < 6; it++)
        acc[ct][it] = __builtin_amdgcn_mfma_f32_16x16x32_bf16(a[ct], b[it], acc[ct][it], 0, 0, 0);
  }
  if (!spass){
    #pragma unroll
    for (int ct = 0; ct < 4; ct++)
      #pragma unroll
      for (int it = 0; it < 6; it++){
        int c0 = wid * 64 + ct * 16 + quad * 4;
        int i = it * 16 + col;
        size_t base = ((size_t)bb * NP + h * 96 + i) * NC + c0;
        uint2 uoh = *(const uint2*)(OH + base);
        uint2 uxn = *(const uint2*)(XN + base);
        float o0 = g * (acc[ct][it][0] + bflo(uoh.x)) + bflo(uxn.x);
        float o1 = g * (acc[ct][it][1] + bfhi(uoh.x)) + bfhi(uxn.x);
        float o2 = g * (acc[ct][it][2] + bflo(uoh.y)) + bflo(uxn.y);
        float o3 = g * (acc[ct][it][3] + bfhi(uoh.y)) + bfhi(uxn.y);
        uint2 u;
        u.x = (unsigned)f2bf(o0) | ((unsigned)f2bf(o1) << 16);
        u.y = (unsigned)f2bf(o2) | ((unsigned)f2bf(o3) << 16);
        *(uint2*)(OtL + base) = u;
      }
  } else {
    float ss = 0.f;
    #pragma unroll
    for (int ct = 0; ct < 4; ct++)
      #pragma unroll
      for (int it = 0; it < 6; it++){
        int c0 = wid * 64 + ct * 16 + quad * 4;
        int i = it * 16 + col;
        size_t base = ((size_t)bb * NP + h * 96 + i) * NC + c0;
        uint2 uoh = *(const uint2*)(OH + base);
        uint2 uxn = *(const uint2*)(XN + base);
        uint2 uot = *(const uint2*)(OtL + base);
        float d0 = bflo(uot.x) - (g * (acc[ct][it][0] + bflo(uoh.x)) + bflo(uxn.x));
        float d1 = bfhi(uot.x) - (g * (acc[ct][it][1] + bfhi(uoh.x)) + bfhi(uxn.x));
        float d2 = bflo(uot.y) - (g * (acc[ct][it][2] + bflo(uoh.y)) + bflo(uxn.y));
        float d3 = bfhi(uot.y) - (g * (acc[ct][it][3] + bfhi(uoh.y)) + bfhi(uxn.y));
        ss += d0 * d0 + d1 * d1 + d2 * d2 + d3 * d3;
      }
    ss = blockReduceSum(ss);
    if (threadIdx.x == 0) atomicAdd(out, ss * (1e-5f / 8.0f));
  }
}

// ---------- host ----------
extern "C" void kernel_launch(void* const* d_in, const int* in_sizes, int n_in,
                              void* d_out, int out_size, void* d_ws, size_t ws_size,
                              hipStream_t stream){
  (void)in_sizes; (void)n_in; (void)out_size;
  const float* S    = (const float*)d_in[0];
  const float* T    = (const float*)d_in[1];
  const float* wcls = (const float*)d_in[2];
  const float* wq   = (const float*)d_in[3];
  const float* bq   = (const float*)d_in[4];
  const float* wk   = (const float*)d_in[5];
  const float* bk   = (const float*)d_in[6];
  const float* wv   = (const float*)d_in[7];
  const float* bv   = (const float*)d_in[8];
  const float* gamma= (const float*)d_in[9];
  float* out = (float*)d_out;

  char* base = (char*)d_ws;
  size_t off = 0;
  auto alloc = [&](size_t b){ size_t o = off; off += (b + 255) & ~(size_t)255; return o; };
  size_t o_ssum = alloc(2 * NC * 4);
  size_t o_ssq  = alloc(2 * NC * 4);
  size_t o_mean = alloc(2 * NC * 4);
  size_t o_inv  = alloc(2 * NC * 4);
  size_t o_wb   = alloc((size_t)NV * NC * 2);
  size_t o_ca   = alloc((size_t)2 * NBAT * NKC * NC * 4);
  size_t fixed = off;
  size_t per_b = (size_t)NP * NC * 2 * 5       // XN + VT1 + VT2 + OH + OtL (bf16)
               + (size_t)NP * NCQ * 2 * 2      // q + k (bf16)
               + (size_t)NP * NL * 2           // att (bf16)
               + (size_t)NKC * NP * 4;         // smca (fp32)
  int NB = 8;
  while (NB > 1 && fixed + (size_t)NB * per_b + 8192 > ws_size) NB >>= 1;

  size_t o_xn  = alloc((size_t)NB * NP * NC * 2);
  size_t o_v1  = alloc((size_t)NB * NP * NC * 2);
  size_t o_v2  = alloc((size_t)NB * NP * NC * 2);
  size_t o_q   = alloc((size_t)NB * NP * NCQ * 2);
  size_t o_k   = alloc((size_t)NB * NP * NCQ * 2);
  size_t o_att = alloc((size_t)NB * NP * NL * 2);
  size_t o_oh  = alloc((size_t)NB * NP * NC * 2);
  size_t o_ot  = alloc((size_t)NB * NP * NC * 2);
  size_t o_sm  = alloc((size_t)NB * NKC * NP * 4);

  float* ssum = (float*)(base + o_ssum);
  float* ssq  = (float*)(base + o_ssq);
  float* mean = (float*)(base + o_mean);
  float* inv  = (float*)(base + o_inv);
  float* ca   = (float*)(base + o_ca);
  float* smca = (float*)(base + o_sm);
  unsigned short* Wb  = (unsigned short*)(base + o_wb);
  unsigned short* XN  = (unsigned short*)(base + o_xn);
  unsigned short* VT1 = (unsigned short*)(base + o_v1);
  unsigned short* VT2 = (unsigned short*)(base + o_v2);
  unsigned short* qbp = (unsigned short*)(base + o_q);
  unsigned short* kbp = (unsigned short*)(base + o_k);
  unsigned short* att = (unsigned short*)(base + o_att);
  unsigned short* OH  = (unsigned short*)(base + o_oh);
  unsigned short* OtL = (unsigned short*)(base + o_ot);

  hipMemsetAsync(d_out, 0, 4, stream);
  hipMemsetAsync(base + o_ssum, 0, 4096, stream);
  hipMemsetAsync(base + o_ca, 0, (size_t)2 * NBAT * NKC * NC * 4, stream);

  k_stats<<<dim3(2 * NC * NBAT), 256, 0, stream>>>(S, T, ssum, ssq);
  k_finalize<<<1, 512, 0, stream>>>(ssum, ssq, mean, inv);
  k_wconv<<<dim3(NV), 256, 0, stream>>>(wv, wq, wk, Wb);

  // per batch-chunk: T pass then S pass (ca accumulated; cc loss fused into S outW)
  for (int b0 = 0; b0 < NBAT; b0 += NB){
    for (int pass = 0; pass < 2; pass++){
      int t = (pass == 0) ? 1 : 0;
      const float* x = t ? T : S;
      k_xn<<<dim3(144, 4, NB), 256, 0, stream>>>(x, b0, mean, inv, t, XN);
      k_caMB<<<dim3(36, NB), 256, 0, stream>>>(XN, wcls, smca);
      k_caSoftmax<<<dim3(NB * NKC), 256, 0, stream>>>(smca);
      k_caOutB<<<dim3(8, NB), 256, 0, stream>>>(XN, smca, ca, t, b0);
      k_v<<<dim3(144, NB), 256, 0, stream>>>(XN, Wb, bv, bq, bk, VT1, qbp, kbp);
      k_vt<<<dim3(NC, NB), 256, 0, stream>>>(VT1, VT2);
      k_eH<<<dim3(96, NB), 256, 0, stream>>>(qbp, kbp, att);
      k_eW<<<dim3(96, NB), 256, 0, stream>>>(qbp, kbp, att);
      k_attSoftmax<<<dim3(NB * 2304), 256, 0, stream>>>(att);
      k_outH<<<dim3(96, NB), 256, 0, stream>>>(VT2, att, OH);
      k_outW<<<dim3(96, NB), 256, 0, stream>>>(VT1, att, OH, OtL, XN,
                                               gamma, pass, out);
    }
  }
  k_caLoss<<<dim3(48), 256, 0, stream>>>(ca, out);
}